// Round 5
// baseline (1402.345 us; speedup 1.0000x reference)
//
#include <hip/hip_runtime.h>
#include <math.h>

#define TWO_PI 6.28318530717958647692f
#define NXD 64
#define NYD 64
#define NZD 40
#define CID 32
#define NJZ 16   // kept z bins: kz = 0..7, 13..20
#define NJY 32   // kept y bins (xy branch): ky = 0..15, 17..32

// workspace slot strides (float2 elements per batch-slot)
#define R1SLOT 2621440ll   // max(T=2097152, S=2621440)
#define R2SLOT 655360ll    // max(V=524288, V2=655360)
#define R3SLOT 2621440ll   // max(P=2097152, P2=2621440, U=655360)

typedef __attribute__((ext_vector_type(8))) short short8;
typedef __attribute__((ext_vector_type(4))) float float4v;

__device__ inline unsigned short f2bf(float f) {
  unsigned u = __builtin_bit_cast(unsigned, f);
  unsigned r = (u + 0x7fffu + ((u >> 16) & 1u)) >> 16;
  return (unsigned short)r;
}

// ---------------- 1x1 conv via MFMA
__global__ __launch_bounds__(256) void k_conv_mfma(const float* __restrict__ X,
    const float* __restrict__ Wc, const float* __restrict__ bias,
    float* __restrict__ out) {
  int t = threadIdx.x;
  int wid = t >> 6, lane = t & 63;
  int l15 = lane & 15, quad = lane >> 4;
  short8 B[2];
  float bb[2];
  for (int nt = 0; nt < 2; ++nt) {
    int o = nt * 16 + l15;
    for (int j = 0; j < 8; ++j) B[nt][j] = (short)f2bf(Wc[o * 32 + quad * 8 + j]);
    bb[nt] = bias[o];
  }
  const int TOT = 40960;
  int wg = blockIdx.x * 4 + wid;
  for (int tt = wg; tt < TOT; tt += gridDim.x * 4) {
    long r0 = (long)tt * 16;
    const float4v* p = (const float4v*)(X + (r0 + l15) * 32 + quad * 8);
    float4v x0 = p[0], x1 = p[1];
    short8 a;
    for (int j = 0; j < 4; ++j) { a[j] = (short)f2bf(x0[j]); a[4 + j] = (short)f2bf(x1[j]); }
    for (int nt = 0; nt < 2; ++nt) {
      float4v acc = {0.f, 0.f, 0.f, 0.f};
      acc = __builtin_amdgcn_mfma_f32_16x16x32_bf16(a, B[nt], acc, 0, 0, 0);
      for (int r = 0; r < 4; ++r)
        out[(r0 + quad * 4 + r) * 32 + nt * 16 + l15] = acc[r] + bb[nt];
    }
  }
}

// ---------------- z projection (shared by xz & yz branches)
__global__ __launch_bounds__(512) void k_zproj(const float* __restrict__ X,
    float2* __restrict__ Tb, int b0) {
  __shared__ float xs[NZD][CID];
  __shared__ float2 tw[NJZ][NZD];
  int t = threadIdx.x;
  int xy = blockIdx.x;
  int b = b0 + blockIdx.z;
  float2* T = Tb + (long)blockIdx.z * R1SLOT;
  const float* src = X + ((long)(b * 4096 + xy)) * NZD * CID;
  for (int k = t; k < NZD * CID; k += 512) xs[k >> 5][k & 31] = src[k];
  for (int k = t; k < NJZ * NZD; k += 512) {
    int j = k / NZD, z = k % NZD;
    int kz = (j < 8) ? j : j + 5;
    int m = (kz * z) % NZD;
    float s_, c_; sincosf(TWO_PI * m / (float)NZD, &s_, &c_);
    tw[j][z] = make_float2(c_, -s_);
  }
  __syncthreads();
  int j = t >> 5, i = t & 31;
  float2 acc = make_float2(0.f, 0.f);
  for (int z = 0; z < NZD; ++z) {
    float v = xs[z][i];
    float2 w = tw[j][z];
    acc.x += v * w.x; acc.y += v * w.y;
  }
  T[((long)xy * NJZ + j) * CID + i] = acc;
}

// ---------------- streaming forward-axis DFT (64 -> 16 modes), amplification-free.
__global__ __launch_bounds__(256) void k_fwddft(const float2* __restrict__ inb,
    float2* __restrict__ Ub, long CS, long SS, long JS) {
  __shared__ float2 tw[64];
  int t = threadIdx.x;
  if (t < 64) {
    float s_, c_; sincosf(TWO_PI * t / 64.0f, &s_, &c_);
    tw[t] = make_float2(c_, -s_);
  }
  int j = blockIdx.x, sc = blockIdx.y;
  int J = gridDim.x, SD = gridDim.y * 8;
  int s = sc * 8 + (t >> 5), i = t & 31;
  const float2* in = inb + (long)blockIdx.z * R1SLOT + (long)j * JS + (long)s * SS + i;
  float2 acc[16];
#pragma unroll
  for (int m = 0; m < 16; ++m) acc[m] = make_float2(0.f, 0.f);
  __syncthreads();
  for (int c = 0; c < 64; ++c) {
    float2 v = in[(long)c * CS];
#pragma unroll
    for (int m = 0; m < 16; ++m) {
      float2 w = tw[(m * c) & 63];
      acc[m].x += v.x * w.x - v.y * w.y;
      acc[m].y += v.x * w.y + v.y * w.x;
    }
  }
  float2* U = Ub + (long)blockIdx.z * R3SLOT;
#pragma unroll
  for (int m = 0; m < 16; ++m)
    U[((long)(m * J + j) * SD + s) * 32 + i] = acc[m];
}

// ---------------- unified channel mode-mix: V[m,j,s,o] = sum_i U[m,j,s,i]*W[m,j][i][o]
__global__ __launch_bounds__(256) void k_mix(const float2* __restrict__ Ub,
    float2* __restrict__ Vb, const float* __restrict__ fw, const float* __restrict__ fw2,
    int jsplit, int JW, long OM, long OJ, long OS, int SD) {
  __shared__ float2 Us[64][32];
  __shared__ float2 Wm[32][32];
  int m = blockIdx.x, j = blockIdx.y, t = threadIdx.x;
  int J = gridDim.y;
  const float2* U = Ub + (long)blockIdx.z * R3SLOT + (long)(m * J + j) * SD * 32;
  for (int k = t; k < SD * 32; k += 256) Us[k >> 5][k & 31] = U[k];
  {
    const float* src = (j < jsplit) ? fw : fw2;
    int jl = (j < jsplit) ? j : j - jsplit;
    for (int k = t; k < 1024; k += 256) {
      int i = k >> 5, o = k & 31;
      const float* p = src + (((i * 32 + o) * 16 + m) * JW + jl) * 2;
      Wm[i][o] = make_float2(p[0], p[1]);
    }
  }
  __syncthreads();
  int o = t & 31, sg = t >> 5;
  float2* V = Vb + (long)blockIdx.z * R2SLOT;
  for (int s = sg; s < SD; s += 8) {
    float2 acc = make_float2(0.f, 0.f);
    for (int i2 = 0; i2 < 32; ++i2) {
      float2 u = Us[s][i2], w = Wm[i2][o];
      acc.x += u.x * w.x - u.y * w.y;
      acc.y += u.x * w.y + u.y * w.x;
    }
    V[(long)m * OM + (long)j * OJ + (long)s * OS + o] = acc;
  }
}

// ---------------- inverse axis DFT (16 modes -> 64), unnormalized
__global__ __launch_bounds__(256) void k_invaxis(const float2* __restrict__ Vb,
    float2* __restrict__ Pb) {
  __shared__ float2 Vs[16][CID];
  __shared__ float2 twp[64];
  int s = blockIdx.x, j = blockIdx.y, t = threadIdx.x;
  const float2* V = Vb + (long)blockIdx.z * R2SLOT;
  float2* P = Pb + (long)blockIdx.z * R3SLOT;
  if (t < 64) {
    float s_, c_; sincosf(TWO_PI * t / 64.0f, &s_, &c_);
    twp[t] = make_float2(c_, s_);
  }
  for (int k = t; k < 512; k += 256) {
    int mm = k >> 5, o = k & 31;
    Vs[mm][o] = V[((long)(mm * 64 + s) * NJZ + j) * CID + o];
  }
  __syncthreads();
  int o = t & 31, vg = t >> 5;
  for (int k = 0; k < 8; ++k) {
    int v = vg + 8 * k;
    float2 acc = make_float2(0.f, 0.f);
    for (int mm = 0; mm < 16; ++mm) {
      float2 w = twp[(mm * v) & 63];
      float2 vv = Vs[mm][o];
      acc.x += vv.x * w.x - vv.y * w.y;
      acc.y += vv.x * w.y + vv.y * w.x;
    }
    P[((long)(v * 64 + s) * NJZ + j) * CID + o] = acc;
  }
}

// ---------------- inverse real-z via MFMA (16 bins -> 40) + RMW accumulate
// per (v, m-chunk): M=256 rows (m=s*32+i), K=32 (k=2*j+part), N=40 (z, 3 tiles)
__global__ __launch_bounds__(256) void k_invzadd_mfma(const float2* __restrict__ Pb,
    float* __restrict__ out, long strideV, long strideS, int b0) {
  __shared__ unsigned short As[256][40];  // [m][k] bf16, row 80B (16B-aligned)
  int t = threadIdx.x;
  int wid = t >> 6, lane = t & 63;
  int l15 = lane & 15, quad = lane >> 4;
  int b = b0 + blockIdx.z;
  int v = blockIdx.y;
  int m0 = blockIdx.x * 256;
  // B frags: k = quad*8 + jj ; n = z = nt*16 + l15
  short8 Bf[3];
  for (int nt = 0; nt < 3; ++nt) {
    int z = nt * 16 + l15;
    int zc = (z < NZD) ? z : 0;
    for (int jj = 0; jj < 8; ++jj) {
      int k = quad * 8 + jj;
      int j = k >> 1, part = k & 1;
      int kz = (j < 8) ? j : j + 5;
      float cj = ((kz == 0 || kz == 20) ? 1.0f : 2.0f) * (1.0f / 2560.0f);
      float s_, c_; sincosf(TWO_PI * ((kz * zc) % NZD) / (float)NZD, &s_, &c_);
      Bf[nt][jj] = (short)f2bf(part ? -cj * s_ : cj * c_);
    }
  }
  // stage A: P[v, s, j, i] -> As[m][2j|part]
  const float2* src = Pb + (long)blockIdx.z * R3SLOT;
  for (int k = t; k < 16 * 256; k += 256) {
    int j = k >> 8, m = k & 255;
    int s = (m0 + m) >> 5, i = m & 31;
    float2 pv = src[((long)(v * 64 + s) * NJZ + j) * CID + i];
    unsigned pk = (unsigned)f2bf(pv.x) | ((unsigned)f2bf(pv.y) << 16);
    *(unsigned*)&As[m][j * 2] = pk;
  }
  __syncthreads();
  float* ob = out + (long)b * NXD * NYD * NZD * CID + (long)v * strideV;
  for (int mt = 0; mt < 4; ++mt) {
    int mrow = wid * 64 + mt * 16 + l15;
    short8 a = *(const short8*)&As[mrow][quad * 8];
    int mb = m0 + wid * 64 + mt * 16 + quad * 4;
    int s = mb >> 5, i0 = mb & 31;
    for (int nt = 0; nt < 3; ++nt) {
      float4v acc = {0.f, 0.f, 0.f, 0.f};
      acc = __builtin_amdgcn_mfma_f32_16x16x32_bf16(a, Bf[nt], acc, 0, 0, 0);
      int z = nt * 16 + l15;
      if (z < NZD) {
        float4v* p = (float4v*)&ob[(long)s * strideS + z * 32 + i0];
        float4v old = *p;
        old.x += acc[0]; old.y += acc[1]; old.z += acc[2]; old.w += acc[3];
        *p = old;
      }
    }
  }
}

// ---------------- xy branch: forward real-y DFT via MFMA (64 -> 32 bins)
__global__ __launch_bounds__(256) void k_fwdy_mfma(const float* __restrict__ X,
    float2* __restrict__ Sb, int b0) {
  __shared__ unsigned short Xs[256][72];  // [m][y] bf16
  __shared__ float2 twtab[64];            // (cos, sin) of 2*pi*a/64
  int t = threadIdx.x;
  int wid = t >> 6, lane = t & 63;
  int l15 = lane & 15, quad = lane >> 4;
  int b = b0 + blockIdx.z;
  int x = blockIdx.y;
  int m0 = blockIdx.x * 256;
  if (t < 64) {
    float s_, c_; sincosf(TWO_PI * t / 64.0f, &s_, &c_);
    twtab[t] = make_float2(c_, s_);
  }
  __syncthreads();
  short8 Bf[2][4];
  for (int nt = 0; nt < 4; ++nt) {
    int n = nt * 16 + l15;
    int jy = n >> 1, part = n & 1;
    int ky = (jy < 16) ? jy : jy + 1;
    for (int kt = 0; kt < 2; ++kt)
      for (int j = 0; j < 8; ++j) {
        int y = kt * 32 + quad * 8 + j;
        float2 w = twtab[(ky * y) & 63];
        Bf[kt][nt][j] = (short)f2bf(part ? -w.y : w.x);
      }
  }
  const float* src = X + (((long)b * 64 + x) * 64) * 1280 + m0;
  for (int k = t; k < 64 * 256; k += 256) {
    int y = k >> 8, m = k & 255;
    Xs[m][y] = f2bf(src[(long)y * 1280 + m]);
  }
  __syncthreads();
  float2* S = Sb + (long)blockIdx.z * R1SLOT + (long)x * (NJY * NZD * CID);
  for (int mt = 0; mt < 4; ++mt) {
    int mrow = wid * 64 + mt * 16 + l15;
    short8 a0 = *(const short8*)&Xs[mrow][quad * 8];
    short8 a1 = *(const short8*)&Xs[mrow][32 + quad * 8];
    for (int nt = 0; nt < 4; ++nt) {
      float4v acc = {0.f, 0.f, 0.f, 0.f};
      acc = __builtin_amdgcn_mfma_f32_16x16x32_bf16(a0, Bf[0][nt], acc, 0, 0, 0);
      acc = __builtin_amdgcn_mfma_f32_16x16x32_bf16(a1, Bf[1][nt], acc, 0, 0, 0);
      int n = nt * 16 + l15, jy = n >> 1, part = n & 1;
      for (int r = 0; r < 4; ++r) {
        int m = m0 + wid * 64 + mt * 16 + quad * 4 + r;
        int z = m >> 5, i = m & 31;
        ((float*)&S[((long)jy * NZD + z) * CID + i])[part] = acc[r];
      }
    }
  }
}

// ---------------- xy branch: inverse x DFT (16 -> 64), unnormalized
__global__ __launch_bounds__(256) void k_invx_xy(const float2* __restrict__ V2b,
    float2* __restrict__ P2b) {
  __shared__ float2 Vs[16][CID];
  __shared__ float2 twp[64];
  int jy = blockIdx.x, z = blockIdx.y, t = threadIdx.x;
  const float2* V2 = V2b + (long)blockIdx.z * R2SLOT;
  float2* P2 = P2b + (long)blockIdx.z * R3SLOT;
  if (t < 64) {
    float s_, c_; sincosf(TWO_PI * t / 64.0f, &s_, &c_);
    twp[t] = make_float2(c_, s_);
  }
  for (int k = t; k < 512; k += 256) {
    int kx = k >> 5, o = k & 31;
    Vs[kx][o] = V2[(((long)kx * NJY + jy) * NZD + z) * CID + o];
  }
  __syncthreads();
  int o = t & 31, xg = t >> 5;
  for (int k = 0; k < 8; ++k) {
    int x = xg + 8 * k;
    float2 acc = make_float2(0.f, 0.f);
    for (int kx = 0; kx < 16; ++kx) {
      float2 w = twp[(kx * x) & 63];
      float2 v = Vs[kx][o];
      acc.x += v.x * w.x - v.y * w.y;
      acc.y += v.x * w.y + v.y * w.x;
    }
    P2[(((long)x * NJY + jy) * NZD + z) * CID + o] = acc;
  }
}

// ---------------- xy branch: inverse real-y via MFMA (32 bins -> 64) + RMW
// per (b,x, m-chunk): M=256 (m=z*32+i), K=64 (k=2*jy+part), N=64 (y)
__global__ __launch_bounds__(256) void k_invyadd_mfma(const float2* __restrict__ P2b,
    float* __restrict__ out, int b0) {
  __shared__ unsigned short As[256][72];  // [m][k] bf16, row 144B (16B-aligned)
  __shared__ float2 twtab[64];
  int t = threadIdx.x;
  int wid = t >> 6, lane = t & 63;
  int l15 = lane & 15, quad = lane >> 4;
  int b = b0 + blockIdx.z;
  int x = blockIdx.y;
  int m0 = blockIdx.x * 256;
  if (t < 64) {
    float s_, c_; sincosf(TWO_PI * t / 64.0f, &s_, &c_);
    twtab[t] = make_float2(c_, s_);
  }
  __syncthreads();
  // B frags: k = kt*32+quad*8+j ; n = y = nt*16+l15
  short8 Bf[2][4];
  for (int nt = 0; nt < 4; ++nt) {
    int y = nt * 16 + l15;
    for (int kt = 0; kt < 2; ++kt)
      for (int j = 0; j < 8; ++j) {
        int k = kt * 32 + quad * 8 + j;
        int jy = k >> 1, part = k & 1;
        int ky = (jy < 16) ? jy : jy + 1;
        float cj = ((ky == 0 || ky == 32) ? 1.0f : 2.0f) * (1.0f / 4096.0f);
        float2 w = twtab[(ky * y) & 63];
        Bf[kt][nt][j] = (short)f2bf(part ? -cj * w.y : cj * w.x);
      }
  }
  // stage A: P2[x, jy, z, i] -> As[m][2jy|part]
  const float2* src = P2b + (long)blockIdx.z * R3SLOT + (long)x * (NJY * NZD * CID);
  for (int k = t; k < 32 * 256; k += 256) {
    int jy = k >> 8, m = k & 255;
    int z = (m0 + m) >> 5, i = m & 31;
    float2 pv = src[((long)jy * NZD + z) * CID + i];
    unsigned pk = (unsigned)f2bf(pv.x) | ((unsigned)f2bf(pv.y) << 16);
    *(unsigned*)&As[m][jy * 2] = pk;
  }
  __syncthreads();
  float* ob = out + (((long)b * 64 + x) * 64) * 1280;  // [y][m]
  for (int mt = 0; mt < 4; ++mt) {
    int mrow = wid * 64 + mt * 16 + l15;
    short8 a0 = *(const short8*)&As[mrow][quad * 8];
    short8 a1 = *(const short8*)&As[mrow][32 + quad * 8];
    int mb = m0 + wid * 64 + mt * 16 + quad * 4;
    for (int nt = 0; nt < 4; ++nt) {
      float4v acc = {0.f, 0.f, 0.f, 0.f};
      acc = __builtin_amdgcn_mfma_f32_16x16x32_bf16(a0, Bf[0][nt], acc, 0, 0, 0);
      acc = __builtin_amdgcn_mfma_f32_16x16x32_bf16(a1, Bf[1][nt], acc, 0, 0, 0);
      int y = nt * 16 + l15;
      float4v* p = (float4v*)&ob[(long)y * 1280 + mb];
      float4v old = *p;
      old.x += acc[0]; old.y += acc[1]; old.z += acc[2]; old.w += acc[3];
      *p = old;
    }
  }
}

// ---------------- FFN via MFMA, in-place on out.
__global__ __launch_bounds__(256) void k_ff_mfma(float* __restrict__ out,
    const float* __restrict__ W0, const float* __restrict__ b0,
    const float* __restrict__ W1, const float* __restrict__ b1) {
  __shared__ unsigned short h1s[4][16 * 64];
  int t = threadIdx.x;
  int wid = t >> 6, lane = t & 63;
  int l15 = lane & 15, quad = lane >> 4;
  short8 B1[4];
  float bb0[4];
  for (int nt = 0; nt < 4; ++nt) {
    int hh = nt * 16 + l15;
    for (int j = 0; j < 8; ++j) B1[nt][j] = (short)f2bf(W0[hh * 32 + quad * 8 + j]);
    bb0[nt] = b0[hh];
  }
  short8 B2[2][2];
  float bb1[2];
  for (int k0 = 0; k0 < 2; ++k0)
    for (int nt = 0; nt < 2; ++nt) {
      int o = nt * 16 + l15;
      for (int j = 0; j < 8; ++j)
        B2[k0][nt][j] = (short)f2bf(W1[o * 64 + k0 * 32 + quad * 8 + j]);
    }
  for (int nt = 0; nt < 2; ++nt) bb1[nt] = b1[nt * 16 + l15];

  const int TOT = 40960;
  int wg = blockIdx.x * 4 + wid;
  unsigned short* hs = h1s[wid];
  for (int tt = wg; tt < TOT; tt += gridDim.x * 4) {
    long r0 = (long)tt * 16;
    const float4v* p = (const float4v*)(out + (r0 + l15) * 32 + quad * 8);
    float4v x0 = p[0], x1 = p[1];
    short8 a1;
    for (int j = 0; j < 4; ++j) { a1[j] = (short)f2bf(x0[j]); a1[4 + j] = (short)f2bf(x1[j]); }
    for (int nt = 0; nt < 4; ++nt) {
      float4v acc = {0.f, 0.f, 0.f, 0.f};
      acc = __builtin_amdgcn_mfma_f32_16x16x32_bf16(a1, B1[nt], acc, 0, 0, 0);
      for (int r = 0; r < 4; ++r) {
        float v = acc[r] + bb0[nt];
        v = v > 0.f ? v : 0.f;
        hs[(quad * 4 + r) * 64 + nt * 16 + l15] = f2bf(v);
      }
    }
    short8 a2[2];
    for (int k0 = 0; k0 < 2; ++k0)
      a2[k0] = *(const short8*)&hs[l15 * 64 + k0 * 32 + quad * 8];
    for (int nt = 0; nt < 2; ++nt) {
      float4v acc = {0.f, 0.f, 0.f, 0.f};
      acc = __builtin_amdgcn_mfma_f32_16x16x32_bf16(a2[0], B2[0][nt], acc, 0, 0, 0);
      acc = __builtin_amdgcn_mfma_f32_16x16x32_bf16(a2[1], B2[1][nt], acc, 0, 0, 0);
      for (int r = 0; r < 4; ++r)
        out[(r0 + quad * 4 + r) * 32 + nt * 16 + l15] = acc[r] + bb1[nt];
    }
  }
}

extern "C" void kernel_launch(void* const* d_in, const int* in_sizes, int n_in,
                              void* d_out, int out_size, void* d_ws, size_t ws_size,
                              hipStream_t stream) {
  const float* X       = (const float*)d_in[0];
  const float* w_w     = (const float*)d_in[1];
  const float* w_b     = (const float*)d_in[2];
  const float* fw_xy   = (const float*)d_in[3];
  const float* fw_yz   = (const float*)d_in[4];
  const float* fw_xz   = (const float*)d_in[5];
  const float* fw2_xy  = (const float*)d_in[6];
  const float* fw2_yz  = (const float*)d_in[7];
  const float* fw2_xz  = (const float*)d_in[8];
  const float* ff_w0   = (const float*)d_in[9];
  const float* ff_b0   = (const float*)d_in[10];
  const float* ff_w1   = (const float*)d_in[11];
  const float* ff_b1   = (const float*)d_in[12];
  float* out = (float*)d_out;
  char* ws = (char*)d_ws;

  const size_t need_full = (size_t)(R1SLOT + R2SLOT + R3SLOT) * 4 * 8;
  bool full = ws_size >= need_full;

  float2 *r1, *r2, *r3;
  if (full) {
    r1 = (float2*)ws;
    r2 = (float2*)(ws + (size_t)R1SLOT * 4 * 8);
    r3 = (float2*)(ws + (size_t)(R1SLOT + R2SLOT) * 4 * 8);
  } else {
    r1 = (float2*)ws;
    r2 = (float2*)(ws + (size_t)R1SLOT * 8);
    r3 = (float2*)(ws + (size_t)(R1SLOT + R2SLOT) * 8);
  }

  k_conv_mfma<<<dim3(2560), dim3(256), 0, stream>>>(X, w_w, w_b, out);

  int nz = full ? 4 : 1;
  int nb = full ? 1 : 4;
  for (int b = 0; b < nb; ++b) {
    // shared z-projection for xz & yz (T in r1)
    k_zproj<<<dim3(4096, 1, nz), dim3(512), 0, stream>>>(X, r1, b);
    // ---- xz branch: contract x. T idx: x*32768 + y*512 + j*32 + i
    k_fwddft<<<dim3(16, 8, nz), dim3(256), 0, stream>>>(r1, r3, 32768, 512, 32);
    k_mix<<<dim3(16, 16, nz), dim3(256), 0, stream>>>(r3, r2, fw_xz, fw2_xz,
        8, 8, 32768, 32, 512, 64);
    k_invaxis<<<dim3(64, 16, nz), dim3(256), 0, stream>>>(r2, r3);
    k_invzadd_mfma<<<dim3(8, 64, nz), dim3(256), 0, stream>>>(r3, out, 64 * 40 * 32, 40 * 32, b);
    // ---- yz branch: contract y. T idx: y*512 + x*32768 + j*32 + i
    k_fwddft<<<dim3(16, 8, nz), dim3(256), 0, stream>>>(r1, r3, 512, 32768, 32);
    k_mix<<<dim3(16, 16, nz), dim3(256), 0, stream>>>(r3, r2, fw_yz, fw2_yz,
        8, 8, 32768, 32, 512, 64);
    k_invaxis<<<dim3(64, 16, nz), dim3(256), 0, stream>>>(r2, r3);
    k_invzadd_mfma<<<dim3(8, 64, nz), dim3(256), 0, stream>>>(r3, out, 40 * 32, 64 * 40 * 32, b);
    // ---- xy branch (S in r1): S idx: x*40960 + jy*1280 + z*32 + i
    k_fwdy_mfma<<<dim3(5, 64, nz), dim3(256), 0, stream>>>(X, r1, b);
    k_fwddft<<<dim3(32, 5, nz), dim3(256), 0, stream>>>(r1, r3, 40960, 32, 1280);
    k_mix<<<dim3(16, 32, nz), dim3(256), 0, stream>>>(r3, r2, fw_xy, fw2_xy,
        16, 16, 40960, 1280, 32, 40);
    k_invx_xy<<<dim3(32, 40, nz), dim3(256), 0, stream>>>(r2, r3);
    k_invyadd_mfma<<<dim3(5, 64, nz), dim3(256), 0, stream>>>(r3, out, b);
  }

  k_ff_mfma<<<dim3(2560), dim3(256), 0, stream>>>(out, ff_w0, ff_b0, ff_w1, ff_b1);
}